// Round 8
// baseline (367.863 us; speedup 1.0000x reference)
//
#include <hip/hip_runtime.h>
#include <stdint.h>

typedef unsigned long long u64;
typedef unsigned int u32;
typedef int v4i  __attribute__((ext_vector_type(4)));
typedef int v16i __attribute__((ext_vector_type(16)));

#define N_IMG 32
#define C_IN  256
#define C_OUT 256
#define H     56
#define W     56
#define HW    (H*W)          // 3136
#define NHW   (N_IMG*HW)     // 100352
#define CHW   (C_IN*HW)      // 802816

// Workspace layout:
//   px  @ 0:        [n][h][w][4] u64 packed sign bits   (3,211,264 B)
//   wpk @ PX_BYTES: [tap][kb][co][32] i8 +-1 weights    (  589,824 B)
//   y   @ Y_OFF:    [n][co][h][w] int16 conv result     (51,380,224 B)
//   partials overlaps px (px dead after conv)
#define PX_BYTES  3211264
#define WPK_BYTES 589824
#define Y_OFF     (PX_BYTES + WPK_BYTES)

// ---------------------------------------------------------------------------
// Pack activations (UNCHANGED, known-good). bit=1 <=> sign(x)==-1.
// ---------------------------------------------------------------------------
__global__ __launch_bounds__(256)
void pack_x_kernel(const float* __restrict__ x, u64* __restrict__ px) {
    int t = blockIdx.x * 256 + threadIdx.x;   // [0, 100352)
    int w4   = t % 14;
    int r    = t / 14;
    int word = r & 3;
    int r2   = r >> 2;
    int h    = r2 % H;
    int n    = r2 / H;
    const float4* src = (const float4*)(x + ((size_t)(n*C_IN + word*64) * HW + h*W + w4*4));
    u64 b0 = 0, b1 = 0, b2 = 0, b3 = 0;
    #pragma unroll 8
    for (int j = 0; j < 64; ++j) {
        float4 v = src[(size_t)j * (HW/4)];
        b0 |= (u64)(__float_as_uint(v.x) >> 31) << j;
        b1 |= (u64)(__float_as_uint(v.y) >> 31) << j;
        b2 |= (u64)(__float_as_uint(v.z) >> 31) << j;
        b3 |= (u64)(__float_as_uint(v.w) >> 31) << j;
    }
    u64* dst = px + (((size_t)((n*H + h)*W + w4*4)) << 2) + word;
    dst[0] = b0; dst[4] = b1; dst[8] = b2; dst[12] = b3;
}

// ---------------------------------------------------------------------------
// Pack weights as +-1 int8 (UNCHANGED):
//   wpk[((tap*8 + kb)*256 + co)*32 + kk] = sign byte of w[co][ci=kb*32+kk][tap]
// ---------------------------------------------------------------------------
__global__ __launch_bounds__(256)
void pack_wpk_kernel(const float* __restrict__ wt, char* __restrict__ wpk) {
    int t = blockIdx.x * 256 + threadIdx.x;   // [0, 18432) = (tap*8+kb)*256+co
    int co = t & 255;
    int tk = t >> 8;          // 0..71
    int tap = tk >> 3;
    int kb  = tk & 7;
    u32* out = (u32*)wpk + t*8;
    #pragma unroll
    for (int g = 0; g < 8; ++g) {
        u32 dw = 0;
        #pragma unroll
        for (int b = 0; b < 4; ++b) {
            int ci = kb*32 + 4*g + b;
            float v = wt[((size_t)(co*C_IN + ci)) * 9 + tap];
            u32 byte = (__float_as_uint(v) >> 31) ? 0xFFu : 0x01u;
            dw |= byte << (8*b);
        }
        out[g] = dw;
    }
}

// ---------------------------------------------------------------------------
// MFMA conv (R7 resubmit): R6 structure, register-allocator fix.
//
// R6 post-mortem: the 8-wave merge delivered its occupancy (17.8->35.3%) and
// halved staging, BUT launch_bounds(512,4) made the allocator target 8
// waves/SIMD by registers -> VGPR_Count=64 < the 64 VGPRs the 4 v16i
// accumulators alone need -> accs SPILLED to scratch in the unrolled K-loop.
// Evidence: WRITE_SIZE 51->211MB, FETCH 8->82MB, 300MB @ 2.05TB/s = the
// whole 147us. Session allocator ledger: (256)->64; (256,2)->104-112 OK;
// (512,4)->64+spill. Fix: launch_bounds(512, 2) — cap 1024, heuristic lands
// ~110 as in R4/R5, no spill. LDS (67.5KB) still gives 2 blocks/CU = 4
// waves/SIMD, the occupancy R6 proved. NOTHING else changed.
//
// Fragment maps (bit-exact verified in R4/R5/R6):
//   A: m=lane&31 (co), k=16*(lane>>5)+e ; B: n=lane&31 (px), same k
//   C/D: col(px)=lane&31, row(co)=(reg&3)+8*(reg>>2)+4*(lane>>5)
// ---------------------------------------------------------------------------
__global__ __launch_bounds__(512, 2)
void conv_mfma_kernel(const u64* __restrict__ px, const char* __restrict__ wpk,
                      short* __restrict__ y) {
    __shared__ char lds[4*66*256];            // 67,584 B -> 2 blocks/CU
    int bx = blockIdx.x;                      // [0, 896) = n*28 + hp
    int n  = bx / 28;
    int h0 = (bx % 28) * 2;
    int tid = threadIdx.x;

    // ---- stage: expand packed bits -> i8 into swizzled LDS ----
    for (int i = tid; i < 4*66; i += 512) {   // (row, w') pairs
        int row = i / 66;
        int wp  = i % 66;
        int hh = h0 + row - 1;
        int ww = wp - 1;
        bool valid = ((unsigned)hh < (unsigned)H) && ((unsigned)ww < (unsigned)W);
        u64 wv0 = 0, wv1 = 0, wv2 = 0, wv3 = 0;
        if (valid) {
            const u64* s = px + (((size_t)((n*H + hh)*W + ww)) << 2);
            wv0 = s[0]; wv1 = s[1]; wv2 = s[2]; wv3 = s[3];
        }
        u32 basev = valid ? 0x01010101u : 0u;  // padding stays 0x00
        char* out = lds + i*256;
        int sw = (wp & 15) << 4;
        u64 wvs[4] = {wv0, wv1, wv2, wv3};
        #pragma unroll
        for (int c4 = 0; c4 < 16; ++c4) {
            u32 bits = (u32)(wvs[c4>>2] >> ((c4&3)*16)) & 0xFFFFu;
            v4i ov;
            #pragma unroll
            for (int d = 0; d < 4; ++d) {
                u32 sel = (bits >> (4*d)) & 0xFu;
                u32 sp  = (sel * 0x204081u) & 0x01010101u;  // bit i -> byte i
                u32 m   = (sp << 8) - (sp << 1);            // 0xFE per set byte
                ov[d] = (int)(basev + m);                   // 0xFF/-1, 0x01/+1, 0x00/pad
            }
            *(v4i*)(out + ((c4*16) ^ sw)) = ov;
        }
    }
    __syncthreads();

    int wid   = tid >> 6;         // 0..7
    int lane  = tid & 63;
    int l31   = lane & 31;
    int lhalf = lane >> 5;
    int lh16  = lhalf << 4;
    int coq   = wid & 3;          // 4 co-quarters x 64 co
    int pxh   = wid >> 2;         // 2 px-halves x 64 px
    int cot   = coq * 64;

    // px-tile geometry: this wave's tiles are strip px [64*pxh+l31, +32)
    int pj0 = pxh*64 + l31;       // tile 2*pxh
    int pj1 = pj0 + 32;           // tile 2*pxh+1
    int r0 = (pj0 >= 56) ? 1 : 0;
    int w0 = pj0 - 56*r0;
    int r1 = (pj1 >= 56) ? 1 : 0;
    int w1 = pj1 - 56*r1; if (w1 > 55) w1 = 55;    // clamp garbage lanes
    int rb0 = r0 * (66*256);
    int rb1 = r1 * (66*256);

    v16i acc00 = {0,0,0,0,0,0,0,0,0,0,0,0,0,0,0,0};   // co-frag0 x tile0
    v16i acc01 = acc00;                                // co-frag0 x tile1
    v16i acc10 = acc00;                                // co-frag1 x tile0
    v16i acc11 = acc00;                                // co-frag1 x tile1

    const v4i* wq = (const v4i*)wpk;

    #pragma unroll
    for (int tap = 0; tap < 9; ++tap) {
        const int dw  = tap % 3;
        const int rof = (tap / 3) * (66*256);
        int wp0 = w0 + dw, wp1 = w1 + dw;
        int sw0 = (wp0 & 15) << 4, sw1 = (wp1 & 15) << 4;
        int a0 = rb0 + rof + wp0*256;
        int a1 = rb1 + rof + wp1*256;
        #pragma unroll
        for (int kb = 0; kb < 8; ++kb) {
            int widx = ((tap*8 + kb)*256 + cot + l31) << 1;
            v4i av0 = wq[widx | lhalf];          // co [cot, cot+32)
            v4i av1 = wq[(widx + 64) | lhalf];   // co [cot+32, cot+64)
            int kof = kb*32 + lh16;
            v4i b0 = *(const v4i*)(lds + a0 + (kof ^ sw0));
            v4i b1 = *(const v4i*)(lds + a1 + (kof ^ sw1));
            acc00 = __builtin_amdgcn_mfma_i32_32x32x32_i8(av0, b0, acc00, 0, 0, 0);
            acc01 = __builtin_amdgcn_mfma_i32_32x32x32_i8(av0, b1, acc01, 0, 0, 0);
            acc10 = __builtin_amdgcn_mfma_i32_32x32x32_i8(av1, b0, acc10, 0, 0, 0);
            acc11 = __builtin_amdgcn_mfma_i32_32x32x32_i8(av1, b1, acc11, 0, 0, 0);
        }
    }

    // ---- store: lanes = consecutive px; tile1 of pxh==1 masked for l31>=16
    size_t yb0 = (size_t)n*CHW + (size_t)(cot + (lhalf << 2))*HW;   // co-frag0
    size_t yb1 = yb0 + (size_t)32*HW;                                // co-frag1
    int hr0 = h0 + r0, hr1 = h0 + r1;
    bool full1 = !(pxh == 1 && l31 >= 16);
    {
        size_t o = yb0 + (size_t)hr0*W + w0;
        #pragma unroll
        for (int rg = 0; rg < 16; ++rg)
            y[o + (size_t)((rg&3) + 8*(rg>>2))*HW] = (short)acc00[rg];
    }
    {
        size_t o = yb1 + (size_t)hr0*W + w0;
        #pragma unroll
        for (int rg = 0; rg < 16; ++rg)
            y[o + (size_t)((rg&3) + 8*(rg>>2))*HW] = (short)acc10[rg];
    }
    if (full1) {
        size_t o = yb0 + (size_t)hr1*W + w1;
        #pragma unroll
        for (int rg = 0; rg < 16; ++rg)
            y[o + (size_t)((rg&3) + 8*(rg>>2))*HW] = (short)acc01[rg];
        o = yb1 + (size_t)hr1*W + w1;
        #pragma unroll
        for (int rg = 0; rg < 16; ++rg)
            y[o + (size_t)((rg&3) + 8*(rg>>2))*HW] = (short)acc11[rg];
    }
}

// ---------------------------------------------------------------------------
// Stats pass (UNCHANGED): one block per (n,co) slab.
// ---------------------------------------------------------------------------
__global__ __launch_bounds__(256)
void stats_kernel(const short* __restrict__ y, long long* __restrict__ partials) {
    int slab = blockIdx.x;                    // n*256 + co
    const int4* ys = (const int4*)(y + (size_t)slab * HW);
    int s = 0, sq = 0;
    for (int i = threadIdx.x; i < HW/8; i += 256) {
        int4 v = ys[i];
        int vv[4] = {v.x, v.y, v.z, v.w};
        #pragma unroll
        for (int k = 0; k < 4; ++k) {
            int lo = (short)(vv[k] & 0xFFFF);
            int hi = (short)(vv[k] >> 16);
            s  += lo + hi;
            sq += lo*lo + hi*hi;
        }
    }
    __shared__ int       rs[256];
    __shared__ long long rq[256];
    rs[threadIdx.x] = s;
    rq[threadIdx.x] = sq;
    __syncthreads();
    for (int off = 128; off > 0; off >>= 1) {
        if (threadIdx.x < off) {
            rs[threadIdx.x] += rs[threadIdx.x + off];
            rq[threadIdx.x] += rq[threadIdx.x + off];
        }
        __syncthreads();
    }
    if (threadIdx.x == 0) {
        partials[2*slab]   = rs[0];
        partials[2*slab+1] = rq[0];
    }
}

// ---------------------------------------------------------------------------
// Apply pass (UNCHANGED): one block per (n,co) slab.
// ---------------------------------------------------------------------------
__global__ __launch_bounds__(256)
void apply_kernel(const short* __restrict__ y, const long long* __restrict__ partials,
                  const float* __restrict__ gamma, const float* __restrict__ beta,
                  float* __restrict__ out) {
    int slab = blockIdx.x;
    int co = slab & 255;
    long long S = 0, SS = 0;
    #pragma unroll 8
    for (int m = 0; m < N_IMG; ++m) {
        S  += partials[2*((m<<8) | co)];
        SS += partials[2*((m<<8) | co) + 1];
    }
    double mean = (double)S  * (1.0 / (double)NHW);
    double var  = (double)SS * (1.0 / (double)NHW) - mean*mean;
    float a = gamma[co] * rsqrtf((float)var + 1e-5f);
    float b = beta[co] - (float)mean * a;

    const int4* ys = (const int4*)(y + (size_t)slab * HW);
    float4*     os = (float4*)(out + (size_t)slab * HW);
    for (int i = threadIdx.x; i < HW/8; i += 256) {
        int4 v = ys[i];
        float4 f0, f1;
        f0.x = a * (float)((short)(v.x & 0xFFFF)) + b;
        f0.y = a * (float)((short)(v.x >> 16))    + b;
        f0.z = a * (float)((short)(v.y & 0xFFFF)) + b;
        f0.w = a * (float)((short)(v.y >> 16))    + b;
        f1.x = a * (float)((short)(v.z & 0xFFFF)) + b;
        f1.y = a * (float)((short)(v.z >> 16))    + b;
        f1.z = a * (float)((short)(v.w & 0xFFFF)) + b;
        f1.w = a * (float)((short)(v.w >> 16))    + b;
        os[2*i]   = f0;
        os[2*i+1] = f1;
    }
}

// ---------------------------------------------------------------------------
extern "C" void kernel_launch(void* const* d_in, const int* in_sizes, int n_in,
                              void* d_out, int out_size, void* d_ws, size_t ws_size,
                              hipStream_t stream) {
    const float* x     = (const float*)d_in[0];
    const float* wt    = (const float*)d_in[1];
    const float* gamma = (const float*)d_in[2];
    const float* beta  = (const float*)d_in[3];
    float* out = (float*)d_out;

    char* ws = (char*)d_ws;
    u64*   px  = (u64*)ws;
    char*  wpk = ws + PX_BYTES;
    short* y   = (short*)(ws + Y_OFF);
    long long* partials = (long long*)ws;   // overlaps px: px dead after conv

    hipLaunchKernelGGL(pack_x_kernel,   dim3(100352/256), dim3(256), 0, stream, x, px);
    hipLaunchKernelGGL(pack_wpk_kernel, dim3(72),         dim3(256), 0, stream, wt, wpk);
    hipLaunchKernelGGL(conv_mfma_kernel,dim3(896),        dim3(512), 0, stream, px, wpk, y);
    hipLaunchKernelGGL(stats_kernel,    dim3(8192),       dim3(256), 0, stream, y, partials);
    hipLaunchKernelGGL(apply_kernel,    dim3(8192),       dim3(256), 0, stream, y, partials, gamma, beta, out);
}

// Round 9
// 285.843 us; speedup vs baseline: 1.2869x; 1.2869x over previous
//
#include <hip/hip_runtime.h>
#include <stdint.h>

typedef unsigned long long u64;
typedef unsigned int u32;
typedef int v4i  __attribute__((ext_vector_type(4)));
typedef int v16i __attribute__((ext_vector_type(16)));

#define N_IMG 32
#define C_IN  256
#define C_OUT 256
#define H     56
#define W     56
#define HW    (H*W)          // 3136
#define NHW   (N_IMG*HW)     // 100352
#define CHW   (C_IN*HW)      // 802816

// Workspace layout:
//   px  @ 0:        [n][h][w][4] u64 packed sign bits   (3,211,264 B)
//   wpk @ PX_BYTES: [tap][kb][co][32] i8 +-1 weights    (  589,824 B)
//   y   @ Y_OFF:    [n][co][h][w] int16 conv result     (51,380,224 B)
//   partials overlaps px (px dead after conv)
#define PX_BYTES  3211264
#define WPK_BYTES 589824
#define Y_OFF     (PX_BYTES + WPK_BYTES)

// ---------------------------------------------------------------------------
// Pack activations (UNCHANGED, known-good). bit=1 <=> sign(x)==-1.
// ---------------------------------------------------------------------------
__global__ __launch_bounds__(256)
void pack_x_kernel(const float* __restrict__ x, u64* __restrict__ px) {
    int t = blockIdx.x * 256 + threadIdx.x;   // [0, 100352)
    int w4   = t % 14;
    int r    = t / 14;
    int word = r & 3;
    int r2   = r >> 2;
    int h    = r2 % H;
    int n    = r2 / H;
    const float4* src = (const float4*)(x + ((size_t)(n*C_IN + word*64) * HW + h*W + w4*4));
    u64 b0 = 0, b1 = 0, b2 = 0, b3 = 0;
    #pragma unroll 8
    for (int j = 0; j < 64; ++j) {
        float4 v = src[(size_t)j * (HW/4)];
        b0 |= (u64)(__float_as_uint(v.x) >> 31) << j;
        b1 |= (u64)(__float_as_uint(v.y) >> 31) << j;
        b2 |= (u64)(__float_as_uint(v.z) >> 31) << j;
        b3 |= (u64)(__float_as_uint(v.w) >> 31) << j;
    }
    u64* dst = px + (((size_t)((n*H + h)*W + w4*4)) << 2) + word;
    dst[0] = b0; dst[4] = b1; dst[8] = b2; dst[12] = b3;
}

// ---------------------------------------------------------------------------
// Pack weights as +-1 int8 (UNCHANGED):
//   wpk[((tap*8 + kb)*256 + co)*32 + kk] = sign byte of w[co][ci=kb*32+kk][tap]
// ---------------------------------------------------------------------------
__global__ __launch_bounds__(256)
void pack_wpk_kernel(const float* __restrict__ wt, char* __restrict__ wpk) {
    int t = blockIdx.x * 256 + threadIdx.x;   // [0, 18432) = (tap*8+kb)*256+co
    int co = t & 255;
    int tk = t >> 8;          // 0..71
    int tap = tk >> 3;
    int kb  = tk & 7;
    u32* out = (u32*)wpk + t*8;
    #pragma unroll
    for (int g = 0; g < 8; ++g) {
        u32 dw = 0;
        #pragma unroll
        for (int b = 0; b < 4; ++b) {
            int ci = kb*32 + 4*g + b;
            float v = wt[((size_t)(co*C_IN + ci)) * 9 + tap];
            u32 byte = (__float_as_uint(v) >> 31) ? 0xFFu : 0x01u;
            dw |= byte << (8*b);
        }
        out[g] = dw;
    }
}

// ---------------------------------------------------------------------------
// MFMA conv (R9): ci-half staging + k-chunk-major LDS -> 4 blocks/CU.
//
// Session ledger: matrix-busy is ~27us in every variant (R4 118us@23%,
// R5 151@17.8, R6 147@18 spill-bound, R8 160@16.5) — the kernel is
// latency-bound at 2 waves/SIMD because 67.5KB LDS caps 2 blocks/CU, and
// (512,*) launch bounds derail the allocator (R6: spilled accs, 211MB
// writes; R8: VGPR=80, residual spill + occupancy collapse).
// This version attacks the cap:
//   - Stage HALF the ci per phase (128): LDS 33.8KB -> 4 blocks/CU.
//     K-loop runs twice (cih=0,1); total expansion work unchanged.
//   - k-chunk-major LDS layout [kc 8][row 4][wp 66][16B]: wave B-read at
//     fixed kc, wp=lane -> contiguous 16B/lane -> conflict-free, no XOR
//     swizzle. (Half-wave kc-plane 2-way alias is free, m136.)
//   - Back to 256-thread blocks, launch_bounds(256,2), R5's verified
//     64co x 64px wave tiles (2 ds_read + 2 A-load -> 4 MFMA): the ONLY
//     allocator regime measured spill-free (VGPR 104-112, R4/R5).
// Occupancy target: min(LDS 4 blocks, VGPR 512/104) = 4 waves/SIMD.
//
// Fragment maps (bit-exact verified R4-R8):
//   A: m=lane&31 (co), k=16*(lane>>5)+e ; B: n=lane&31 (px), same k
//   C/D: col(px)=lane&31, row(co)=(reg&3)+8*(rg>>2)+4*(lane>>5)
// ---------------------------------------------------------------------------
__global__ __launch_bounds__(256, 2)
void conv_mfma_kernel(const u64* __restrict__ px, const char* __restrict__ wpk,
                      short* __restrict__ y) {
    // [kc 8][row 4][wp 66][16B] = 33,792 B
    __shared__ char lds[8*4*66*16];
    int bx = blockIdx.x;                      // [0, 896) = n*28 + hp
    int n  = bx / 28;
    int h0 = (bx % 28) * 2;
    int cobase = blockIdx.y * 128;
    int tid = threadIdx.x;

    int wid   = tid >> 6;         // 0..3
    int lane  = tid & 63;
    int l31   = lane & 31;
    int lhalf = lane >> 5;
    int coq   = wid & 1;          // 2 co-halves x 64 co
    int pxh   = wid >> 1;         // 2 px-halves x 64 px
    int cot   = cobase + coq*64;

    // px-tile geometry: this wave's tiles are strip px [64*pxh+l31, +32)
    int pj0 = pxh*64 + l31;       // tile 2*pxh
    int pj1 = pj0 + 32;           // tile 2*pxh+1
    int r0 = (pj0 >= 56) ? 1 : 0;
    int w0 = pj0 - 56*r0;
    int r1 = (pj1 >= 56) ? 1 : 0;
    int w1 = pj1 - 56*r1; if (w1 > 55) w1 = 55;    // clamp garbage lanes

    v16i acc00 = {0,0,0,0,0,0,0,0,0,0,0,0,0,0,0,0};   // co-frag0 x tile0
    v16i acc01 = acc00;                                // co-frag0 x tile1
    v16i acc10 = acc00;                                // co-frag1 x tile0
    v16i acc11 = acc00;                                // co-frag1 x tile1

    const v4i* wq = (const v4i*)wpk;

    #pragma unroll 1
    for (int cih = 0; cih < 2; ++cih) {
        // ---- stage ci-half: expand 128 bits -> 8 k-chunks of 16B ----
        if (cih) __syncthreads();             // all reads of prev half done
        for (int i = tid; i < 4*66; i += 256) {   // i = row*66 + wp
            int row = i / 66;
            int wp  = i % 66;
            int hh = h0 + row - 1;
            int ww = wp - 1;
            bool valid = ((unsigned)hh < (unsigned)H) && ((unsigned)ww < (unsigned)W);
            u64 wv0 = 0, wv1 = 0;
            if (valid) {
                const u64* s = px + (((size_t)((n*H + hh)*W + ww)) << 2) + cih*2;
                wv0 = s[0]; wv1 = s[1];
            }
            u32 basev = valid ? 0x01010101u : 0u;  // padding stays 0x00
            u64 wvs[2] = {wv0, wv1};
            #pragma unroll
            for (int kc = 0; kc < 8; ++kc) {
                u32 bits = (u32)(wvs[kc>>2] >> ((kc&3)*16)) & 0xFFFFu;
                v4i ov;
                #pragma unroll
                for (int d = 0; d < 4; ++d) {
                    u32 sel = (bits >> (4*d)) & 0xFu;
                    u32 sp  = (sel * 0x204081u) & 0x01010101u;  // bit i -> byte i
                    u32 m   = (sp << 8) - (sp << 1);            // 0xFE per set byte
                    ov[d] = (int)(basev + m);   // 0xFF/-1, 0x01/+1, 0x00/pad
                }
                *(v4i*)(lds + ((kc*264 + i) << 4)) = ov;
            }
        }
        __syncthreads();

        // ---- compute: 9 taps x 4 kb (this ci-half) x 4 MFMA ----
        #pragma unroll
        for (int tap = 0; tap < 9; ++tap) {
            const int dw = tap % 3;
            const int rr = tap / 3;
            int i0 = (((r0 + rr)*66) + (w0 + dw)) << 4;
            int i1 = (((r1 + rr)*66) + (w1 + dw)) << 4;
            #pragma unroll
            for (int kb = 0; kb < 4; ++kb) {
                int kbg = cih*4 + kb;
                int widx = ((tap*8 + kbg)*256 + cot + l31) << 1;
                v4i av0 = wq[widx | lhalf];          // co [cot, cot+32)
                v4i av1 = wq[(widx + 64) | lhalf];   // co [cot+32, cot+64)
                int kc = kb*2 + lhalf;
                v4i b0 = *(const v4i*)(lds + kc*4224 + i0);
                v4i b1 = *(const v4i*)(lds + kc*4224 + i1);
                acc00 = __builtin_amdgcn_mfma_i32_32x32x32_i8(av0, b0, acc00, 0, 0, 0);
                acc01 = __builtin_amdgcn_mfma_i32_32x32x32_i8(av0, b1, acc01, 0, 0, 0);
                acc10 = __builtin_amdgcn_mfma_i32_32x32x32_i8(av1, b0, acc10, 0, 0, 0);
                acc11 = __builtin_amdgcn_mfma_i32_32x32x32_i8(av1, b1, acc11, 0, 0, 0);
            }
        }
    }

    // ---- store: lanes = consecutive px; tile1 of pxh==1 masked for l31>=16
    size_t yb0 = (size_t)n*CHW + (size_t)(cot + (lhalf << 2))*HW;   // co-frag0
    size_t yb1 = yb0 + (size_t)32*HW;                                // co-frag1
    int hr0 = h0 + r0, hr1 = h0 + r1;
    bool full1 = !(pxh == 1 && l31 >= 16);
    {
        size_t o = yb0 + (size_t)hr0*W + w0;
        #pragma unroll
        for (int rg = 0; rg < 16; ++rg)
            y[o + (size_t)((rg&3) + 8*(rg>>2))*HW] = (short)acc00[rg];
    }
    {
        size_t o = yb1 + (size_t)hr0*W + w0;
        #pragma unroll
        for (int rg = 0; rg < 16; ++rg)
            y[o + (size_t)((rg&3) + 8*(rg>>2))*HW] = (short)acc10[rg];
    }
    if (full1) {
        size_t o = yb0 + (size_t)hr1*W + w1;
        #pragma unroll
        for (int rg = 0; rg < 16; ++rg)
            y[o + (size_t)((rg&3) + 8*(rg>>2))*HW] = (short)acc01[rg];
        o = yb1 + (size_t)hr1*W + w1;
        #pragma unroll
        for (int rg = 0; rg < 16; ++rg)
            y[o + (size_t)((rg&3) + 8*(rg>>2))*HW] = (short)acc11[rg];
    }
}

// ---------------------------------------------------------------------------
// Stats pass (UNCHANGED): one block per (n,co) slab.
// ---------------------------------------------------------------------------
__global__ __launch_bounds__(256)
void stats_kernel(const short* __restrict__ y, long long* __restrict__ partials) {
    int slab = blockIdx.x;                    // n*256 + co
    const int4* ys = (const int4*)(y + (size_t)slab * HW);
    int s = 0, sq = 0;
    for (int i = threadIdx.x; i < HW/8; i += 256) {
        int4 v = ys[i];
        int vv[4] = {v.x, v.y, v.z, v.w};
        #pragma unroll
        for (int k = 0; k < 4; ++k) {
            int lo = (short)(vv[k] & 0xFFFF);
            int hi = (short)(vv[k] >> 16);
            s  += lo + hi;
            sq += lo*lo + hi*hi;
        }
    }
    __shared__ int       rs[256];
    __shared__ long long rq[256];
    rs[threadIdx.x] = s;
    rq[threadIdx.x] = sq;
    __syncthreads();
    for (int off = 128; off > 0; off >>= 1) {
        if (threadIdx.x < off) {
            rs[threadIdx.x] += rs[threadIdx.x + off];
            rq[threadIdx.x] += rq[threadIdx.x + off];
        }
        __syncthreads();
    }
    if (threadIdx.x == 0) {
        partials[2*slab]   = rs[0];
        partials[2*slab+1] = rq[0];
    }
}

// ---------------------------------------------------------------------------
// Apply pass (UNCHANGED): one block per (n,co) slab.
// ---------------------------------------------------------------------------
__global__ __launch_bounds__(256)
void apply_kernel(const short* __restrict__ y, const long long* __restrict__ partials,
                  const float* __restrict__ gamma, const float* __restrict__ beta,
                  float* __restrict__ out) {
    int slab = blockIdx.x;
    int co = slab & 255;
    long long S = 0, SS = 0;
    #pragma unroll 8
    for (int m = 0; m < N_IMG; ++m) {
        S  += partials[2*((m<<8) | co)];
        SS += partials[2*((m<<8) | co) + 1];
    }
    double mean = (double)S  * (1.0 / (double)NHW);
    double var  = (double)SS * (1.0 / (double)NHW) - mean*mean;
    float a = gamma[co] * rsqrtf((float)var + 1e-5f);
    float b = beta[co] - (float)mean * a;

    const int4* ys = (const int4*)(y + (size_t)slab * HW);
    float4*     os = (float4*)(out + (size_t)slab * HW);
    for (int i = threadIdx.x; i < HW/8; i += 256) {
        int4 v = ys[i];
        float4 f0, f1;
        f0.x = a * (float)((short)(v.x & 0xFFFF)) + b;
        f0.y = a * (float)((short)(v.x >> 16))    + b;
        f0.z = a * (float)((short)(v.y & 0xFFFF)) + b;
        f0.w = a * (float)((short)(v.y >> 16))    + b;
        f1.x = a * (float)((short)(v.z & 0xFFFF)) + b;
        f1.y = a * (float)((short)(v.z >> 16))    + b;
        f1.z = a * (float)((short)(v.w & 0xFFFF)) + b;
        f1.w = a * (float)((short)(v.w >> 16))    + b;
        os[2*i]   = f0;
        os[2*i+1] = f1;
    }
}

// ---------------------------------------------------------------------------
extern "C" void kernel_launch(void* const* d_in, const int* in_sizes, int n_in,
                              void* d_out, int out_size, void* d_ws, size_t ws_size,
                              hipStream_t stream) {
    const float* x     = (const float*)d_in[0];
    const float* wt    = (const float*)d_in[1];
    const float* gamma = (const float*)d_in[2];
    const float* beta  = (const float*)d_in[3];
    float* out = (float*)d_out;

    char* ws = (char*)d_ws;
    u64*   px  = (u64*)ws;
    char*  wpk = ws + PX_BYTES;
    short* y   = (short*)(ws + Y_OFF);
    long long* partials = (long long*)ws;   // overlaps px: px dead after conv

    hipLaunchKernelGGL(pack_x_kernel,   dim3(100352/256), dim3(256), 0, stream, x, px);
    hipLaunchKernelGGL(pack_wpk_kernel, dim3(72),         dim3(256), 0, stream, wt, wpk);
    hipLaunchKernelGGL(conv_mfma_kernel,dim3(896, 2),     dim3(256), 0, stream, px, wpk, y);
    hipLaunchKernelGGL(stats_kernel,    dim3(8192),       dim3(256), 0, stream, y, partials);
    hipLaunchKernelGGL(apply_kernel,    dim3(8192),       dim3(256), 0, stream, y, partials, gamma, beta, out);
}